// Round 8
// baseline (80.788 us; speedup 1.0000x reference)
//
#include <hip/hip_runtime.h>

#define NTHREADS 1024
#define NBLOCKS 256

typedef short bf16x8 __attribute__((ext_vector_type(8)));
typedef short bf16x4 __attribute__((ext_vector_type(4)));
typedef float f32x4  __attribute__((ext_vector_type(4)));
#define MFMA16(a,b,c) __builtin_amdgcn_mfma_f32_16x16x32_bf16(a,b,c,0,0,0)

// split-bf16: hi = rtne_bf16(w), lo = rtne_bf16(w - hi); hi+lo ~ w to 2^-17
__device__ __forceinline__ void splitbf(float f, ushort& h, ushort& l) {
    unsigned u = __float_as_uint(f);
    unsigned r = u + 0x7FFFu + ((u >> 16) & 1u);
    h = (ushort)(r >> 16);
    float fl = f - __uint_as_float(((unsigned)h) << 16);
    unsigned ul = __float_as_uint(fl);
    unsigned rl = ul + 0x7FFFu + ((ul >> 16) & 1u);
    l = (ushort)(rl >> 16);
}

__device__ __forceinline__ void load_wfrag(const float* __restrict__ Wrow,
                                           bf16x8& hi, bf16x8& lo) {
    #pragma unroll
    for (int j = 0; j < 8; ++j) {
        ushort h, l;
        splitbf(Wrow[j], h, l);
        hi[j] = (short)h;
        lo[j] = (short)l;
    }
}

// exact f32->bf16 bit-truncate: valid for exactly-representable values (0,1,2)
__device__ __forceinline__ ushort f2bf(float f) {
    return (ushort)(__float_as_uint(f) >> 16);
}

// In-lane 4-step LIF, float spikes out (identical rounding to all rounds)
__device__ __forceinline__ void lif4(const f32x4& c, float bias,
                                     float& v, float* __restrict__ my) {
    #pragma unroll
    for (int s2 = 0; s2 < 4; ++s2) {
        float cur = c[s2] + bias;
        float vn = fmaf(0.5f, cur - v, v);
        bool fire = (vn >= 1.0f);
        v = fire ? 0.0f : vn;
        my[s2] = fire ? 1.0f : 0.0f;
    }
}

// In-lane 4-step LIF, bf16 spike words out (0x3F80 == bf16(1.0))
__device__ __forceinline__ void lif4u(const f32x4& c, float bias,
                                      float& v, ushort* __restrict__ my) {
    #pragma unroll
    for (int s2 = 0; s2 < 4; ++s2) {
        float cur = c[s2] + bias;
        float vn = fmaf(0.5f, cur - v, v);
        bool fire = (vn >= 1.0f);
        v = fire ? 0.0f : vn;
        my[s2] = fire ? (ushort)0x3F80 : (ushort)0;
    }
}

// pack 4 exactly-representable floats to 4 bf16 and store 8B
__device__ __forceinline__ void pack_store4(char* addr, const float* m) {
    uint2 w;
    w.x = (__float_as_uint(m[0]) >> 16) | (__float_as_uint(m[1]) & 0xFFFF0000u);
    w.y = (__float_as_uint(m[2]) >> 16) | (__float_as_uint(m[3]) & 0xFFFF0000u);
    *(uint2*)addr = w;
}

// 16-wave in-lane-LIF pipeline, 2 quads (8 steps) per barrier, literal ring
// phases: 256 blocks x 1024 threads, 4 batch rows/block, 4 waves/SIMD.
// Spike tiles [16 slots][K] bf16, slot = 4*brow + step. ALL rings depth-8
// quads (slot = quad & 7). Beat b processes quads {2b-LAG, 2b-LAG+1},
// LAG = 0/2/4/6/8 for S1/S2/S3/S4/S5. 36 beats, ONE barrier each.
// Roles (R2 map): W0-1:S1(2 tiles)+S5 t6/7  W2-3:S2  W4-5:S3+h  W6-9:S4
// W10-15:S5.
// This is the verified 76.2us R2 body EXACTLY (ledger: R6 role-remap -2us,
// R7 dual-acc -3.4us — both reverted) with ONE zero-risk addition: role-0
// waves (the S1+S5 straggler that prices every barrier) run the main loop
// at s_setprio(1); set once before the loop, cleared after. Targets
// barrier-skew (beat ~4300cyc vs ~1000cyc issue work).
__global__ __launch_bounds__(NTHREADS, 1) void snn_oct(
    const float* __restrict__ x,
    const float* __restrict__ l1_w,  const float* __restrict__ l1_b,
    const float* __restrict__ r1_w1, const float* __restrict__ r1_b1,
    const float* __restrict__ r1_w2, const float* __restrict__ r1_b2,
    const float* __restrict__ r2_w1, const float* __restrict__ r2_b1,
    const float* __restrict__ r2_w2, const float* __restrict__ r2_b2,
    const float* __restrict__ r2_dw, const float* __restrict__ r2_db,
    const float* __restrict__ wv,    const float* __restrict__ bv,
    const float* __restrict__ wo,    const float* __restrict__ bo,
    const float* __restrict__ fc_w,  const float* __restrict__ fc_b,
    float* __restrict__ out)
{
    // curpre: [14 quad][4 brow][64 n][4 s] f32 = 57344 B; epilogue scratch.
    __shared__ __align__(16) float curpre[14 * 1024];
    // main loop: s1[8][2048] | cp[8][2048] | s2[8][2048] | h[8][2048] | s4[8][4096]
    // phase 0/1 staging (aliased, dead before main loop):
    //   [0,4608) xstage f32 [4][288] | [4608,23296) x bf16 4-shift copies
    //   [23296,82688) l1_w split bf16 (stride 232) | [82688,82944) l1_b f32
    __shared__ __align__(16) char sbuf[98304];

    const int tid  = threadIdx.x;
    const int blk  = blockIdx.x;
    const int lane = tid & 63;
    const int wvi  = tid >> 6;         // wave 0..15
    const int g    = lane >> 4;        // k-group (consumer) / brow (producer)
    const int l16  = lane & 15;        // A-row slot (consumer) / neuron (D col)

    char* sb_s1 = sbuf;                // 8 x 2048
    char* sb_cp = sbuf + 16384;        // 8 x 2048 (uint2 per (tile,g,l16))
    char* sb_s2 = sbuf + 32768;        // 8 x 2048
    char* sb_h  = sbuf + 49152;        // 8 x 2048
    char* sb_s4 = sbuf + 65536;        // 8 x 4096

    // ---------------- phase 0: stage x (f32) + split-bf16 l1 weights -------
    {
        float* xstage = (float*)sbuf;    // [4][288]
        for (int idx = tid; idx < 4 * 288; idx += NTHREADS) {
            int r = idx / 288, tt2 = idx - r * 288;
            xstage[idx] = (tt2 < 256) ? x[(blk * 4 + r) * 256 + tt2] : 0.0f;
        }
        uint* whw = (uint*)(sbuf + 23296);
        uint* wlw = (uint*)(sbuf + 52992);
        for (int idx = tid; idx < 64 * 116; idx += NTHREADS) {
            int n = idx / 116, kp = idx - n * 116;
            int k0 = kp * 2;
            float f0 = (k0 < 201)     ? l1_w[n * 201 + k0]     : 0.0f;
            float f1 = (k0 + 1 < 201) ? l1_w[n * 201 + k0 + 1] : 0.0f;
            ushort h0, l0, h1, l1v;
            splitbf(f0, h0, l0); splitbf(f1, h1, l1v);
            whw[(n * 232 + k0) >> 1] = (uint)h0 | ((uint)h1 << 16);
            wlw[(n * 232 + k0) >> 1] = (uint)l0 | ((uint)l1v << 16);
        }
        if (tid < 64) ((float*)(sbuf + 82688))[tid] = l1_b[tid];
    }
    __syncthreads();

    // ---------------- phase 0b: build 4 shifted bf16 copies of x ----------
    {
        const float* xstage = (const float*)sbuf;
        for (int idx = tid; idx < 4 * 4 * 144; idx += NTHREADS) {
            int c = idx / 576;              // shift 0..3
            int rem = idx - c * 576;
            int r = rem / 144, ep = rem - r * 144;
            int i0 = ep * 2;
            int j0 = i0 + c;
            float f0 = (j0 < 288)     ? xstage[r * 288 + j0]     : 0.0f;
            float f1 = (j0 + 1 < 288) ? xstage[r * 288 + j0 + 1] : 0.0f;
            ushort h0, l0, h1, l1v;
            splitbf(f0, h0, l0); splitbf(f1, h1, l1v);
            *(uint*)(sbuf + 4608 + (c * 4 + r) * 584 + i0 * 2) =
                (uint)h0 | ((uint)h1 << 16);
            *(uint*)(sbuf + 4608 + (16 + c * 4 + r) * 584 + i0 * 2) =
                (uint)l0 | ((uint)l1v << 16);
        }
    }
    __syncthreads();

    // ---------------- phase 1: layer-1 precompute via MFMA ----------------
    {
        const int r1 = wvi & 3;
        const int tt = wvi >> 2;
        const int t0 = tt << 4;
        const int cc2 = l16 & 3;
        const char* xh_base = sbuf + 4608 + (cc2 * 4 + r1) * 584;
        const char* xl_base = xh_base + 16 * 584;
        const int eb = (t0 + (l16 & ~3) + g * 8) * 2;
        const char* whb = sbuf + 23296 + (l16 * 232 + g * 8) * 2;
        const char* wlb = whb + 29696;
        const float* blds = (const float*)(sbuf + 82688);

        f32x4 accp[4];
        #pragma unroll
        for (int nt = 0; nt < 4; ++nt)
            accp[nt] = *(const f32x4*)(blds + nt * 16 + g * 4);

        #pragma unroll
        for (int kt = 0; kt < 7; ++kt) {
            const int xo = eb + kt * 64;
            bf16x4 ha = *(const bf16x4*)(xh_base + xo);
            bf16x4 hb = *(const bf16x4*)(xh_base + xo + 8);
            bf16x4 la = *(const bf16x4*)(xl_base + xo);
            bf16x4 lb = *(const bf16x4*)(xl_base + xo + 8);
            bf16x8 xh8 = __builtin_shufflevector(ha, hb, 0, 1, 2, 3, 4, 5, 6, 7);
            bf16x8 xl8 = __builtin_shufflevector(la, lb, 0, 1, 2, 3, 4, 5, 6, 7);
            #pragma unroll
            for (int nt = 0; nt < 4; ++nt) {
                const int wo2 = nt * 7424 + kt * 64;
                bf16x8 wwh = *(const bf16x8*)(whb + wo2);
                bf16x8 wwl = *(const bf16x8*)(wlb + wo2);
                accp[nt] = MFMA16(wwh, xh8, accp[nt]);
                accp[nt] = MFMA16(wwh, xl8, accp[nt]);
                accp[nt] = MFMA16(wwl, xh8, accp[nt]);
            }
        }
        if (!(tt == 3 && l16 >= 8)) {
            const int t = t0 + l16;
            float* cp = curpre + (t >> 2) * 1024 + r1 * 256 + (t & 3);
            #pragma unroll
            for (int nt = 0; nt < 4; ++nt) {
                #pragma unroll
                for (int j = 0; j < 4; ++j)
                    cp[(nt * 16 + g * 4 + j) * 4] = accp[nt][j];
            }
        }
    }
    __syncthreads();

    // ---------------- consumer A-read addressing (XOR-swizzled) ----------
    const int XS = (l16 & 7) << 4;
    int rdA[2], rdB[4];
    #pragma unroll
    for (int kt = 0; kt < 2; ++kt)
        rdA[kt] = (l16 << 7) + (((kt << 6) | (g << 4)) ^ XS);
    #pragma unroll
    for (int kt = 0; kt < 4; ++kt)
        rdB[kt] = (l16 << 8) + (((kt << 6) | (g << 4)) ^ XS);

    // ---------------- roles + weights (R2 mapping) ----------------
    int role, bt;
    if (wvi < 2)       { role = 0; bt = wvi * 2; }        // S1 + S5 tile 6+wvi
    else if (wvi < 4)  { role = 1; bt = (wvi - 2) * 2; }
    else if (wvi < 6)  { role = 2; bt = (wvi - 4) * 2; }
    else if (wvi < 10) { role = 3; bt = (wvi - 6) * 2; }
    else               { role = 4; bt = wvi - 10; }

    bf16x8 wh[4], wl[4];
    float bias[2] = {0, 0};
    float bias5 = 0.0f;
    int t5 = 0;
    if (role == 1 || role == 2) {
        const float* W = (role == 1) ? r1_w1 : r1_w2;
        const float* B = (role == 1) ? r1_b1 : r1_b2;
        #pragma unroll
        for (int t = 0; t < 2; ++t) {
            #pragma unroll
            for (int kt = 0; kt < 2; ++kt)
                load_wfrag(W + ((bt + t) * 16 + l16) * 64 + kt * 32 + g * 8,
                           wh[t * 2 + kt], wl[t * 2 + kt]);
            bias[t] = B[(bt + t) * 16 + l16];
        }
    } else if (role == 3) {
        #pragma unroll
        for (int t = 0; t < 2; ++t) {
            #pragma unroll
            for (int kt = 0; kt < 2; ++kt)
                load_wfrag(r2_w1 + ((bt + t) * 16 + l16) * 64 + kt * 32 + g * 8,
                           wh[t * 2 + kt], wl[t * 2 + kt]);
            bias[t] = r2_b1[(bt + t) * 16 + l16];
        }
    } else {                               // role 0 (t5 = 6+wvi) or 4 (t5 = bt)
        t5 = (role == 0) ? (6 + wvi) : bt;
        #pragma unroll
        for (int kt = 0; kt < 4; ++kt)
            load_wfrag(r2_w2 + (t5 * 16 + l16) * 128 + kt * 32 + g * 8,
                       wh[kt], wl[kt]);
        bias5 = r2_b2[t5 * 16 + l16];
    }

    // ---------------- thread-invariant store offsets ----------------
    int sto[2][4];
    {
        const int rb = (role == 3) ? 8 : 7;
        #pragma unroll
        for (int t = 0; t < 2; ++t) {
            const int cb = ((bt + t) * 16 + l16) * 2;
            #pragma unroll
            for (int s2 = 0; s2 < 4; ++s2) {
                const int row = 4 * g + s2;
                sto[t][s2] = (row << rb) + (cb ^ ((row & 7) << 4));
            }
        }
    }
    const int cpb = (g << 7) + (l16 << 3);

    float v[2] = {0, 0}, acc[2] = {0, 0};
    float v5 = 0.0f, acc5 = 0.0f;
    float cur55[2] = {0, 0};

    // ---------------- beat body: 2 quads per stage, ring phase jm literal --
    auto do_beat2 = [&](const int b, const int jm, const bool steady,
                        const bool sat) __attribute__((always_inline)) {
        if (role == 0) {
            #pragma unroll
            for (int u = 0; u < 2; ++u) {            // S1 quads 2b, 2b+1
                const int q = 2 * b + u;
                if (steady || q <= 63) {
                    char* dst = sb_s1 + (((2 * jm + u) & 7) << 11);
                    char* cpy = sb_cp + (((2 * jm + u) & 7) << 11) + cpb;
                    #pragma unroll
                    for (int t = 0; t < 2; ++t) {
                        const int ta = bt + t;
                        f32x4 c;
                        if (!sat && q <= 13) {
                            c = *(const f32x4*)(curpre + (q << 10) + (g << 8) +
                                                ((ta * 16 + l16) << 2));
                            if (q == 13) cur55[t] = c[3];
                        } else {
                            c[0] = cur55[t]; c[1] = cur55[t];
                            c[2] = cur55[t]; c[3] = cur55[t];
                        }
                        float my[4];
                        lif4(c, 0.0f, v[t], my);
                        #pragma unroll
                        for (int s2 = 0; s2 < 4; ++s2)
                            *(ushort*)(dst + sto[t][s2]) = f2bf(my[s2]);
                        pack_store4(cpy + ta * 512, my);
                    }
                }
            }
            #pragma unroll
            for (int u = 0; u < 2; ++u) {            // S5 quads 2b-8, 2b-7
                const int q = 2 * b - 8 + u;
                if (steady || q >= 0) {
                    const char* src = sb_s4 + (((2 * jm + u) & 7) << 12);
                    bf16x8 a4[4];
                    #pragma unroll
                    for (int kt = 0; kt < 4; ++kt)
                        a4[kt] = *(const bf16x8*)(src + rdB[kt]);
                    f32x4 c = {0, 0, 0, 0};
                    #pragma unroll
                    for (int kt = 0; kt < 4; ++kt) {
                        c = MFMA16(a4[kt], wh[kt], c);
                        c = MFMA16(a4[kt], wl[kt], c);
                    }
                    float my5[4];
                    lif4(c, bias5, v5, my5);
                    acc5 += (my5[0] + my5[1]) + (my5[2] + my5[3]);
                }
            }
        } else if (role == 1) {                      // S2 quads 2b-2, 2b-1
            #pragma unroll
            for (int u = 0; u < 2; ++u) {
                const int q = 2 * b - 2 + u;
                if (steady || (q >= 0 && q <= 63)) {
                    const char* src = sb_s1 + (((2 * jm + u + 6) & 7) << 11);
                    bf16x8 a0 = *(const bf16x8*)(src + rdA[0]);
                    bf16x8 a1 = *(const bf16x8*)(src + rdA[1]);
                    char* dst = sb_s2 + (((2 * jm + u + 6) & 7) << 11);
                    #pragma unroll
                    for (int t = 0; t < 2; ++t) {
                        f32x4 c = {0, 0, 0, 0};
                        c = MFMA16(a0, wh[t*2+0], c); c = MFMA16(a0, wl[t*2+0], c);
                        c = MFMA16(a1, wh[t*2+1], c); c = MFMA16(a1, wl[t*2+1], c);
                        ushort my[4];
                        lif4u(c, bias[t], v[t], my);
                        #pragma unroll
                        for (int s2 = 0; s2 < 4; ++s2)
                            *(ushort*)(dst + sto[t][s2]) = my[s2];
                    }
                }
            }
        } else if (role == 2) {                      // S3 + h quads 2b-4, 2b-3
            #pragma unroll
            for (int u = 0; u < 2; ++u) {
                const int q = 2 * b - 4 + u;
                if (steady || (q >= 0 && q <= 63)) {
                    const char* src = sb_s2 + (((2 * jm + u + 4) & 7) << 11);
                    const char* cpy = sb_cp + (((2 * jm + u + 4) & 7) << 11) + cpb;
                    bf16x8 a0 = *(const bf16x8*)(src + rdA[0]);
                    bf16x8 a1 = *(const bf16x8*)(src + rdA[1]);
                    char* dst = sb_h + (((2 * jm + u + 4) & 7) << 11);
                    #pragma unroll
                    for (int t = 0; t < 2; ++t) {
                        const int ta = bt + t;
                        f32x4 c = {0, 0, 0, 0};
                        c = MFMA16(a0, wh[t*2+0], c); c = MFMA16(a0, wl[t*2+0], c);
                        c = MFMA16(a1, wh[t*2+1], c); c = MFMA16(a1, wl[t*2+1], c);
                        float my[4];
                        lif4(c, bias[t], v[t], my);
                        const uint2 s1w = *(const uint2*)(cpy + ta * 512);
                        float hh[4];
                        hh[0] = my[0] + __uint_as_float(s1w.x << 16);
                        hh[1] = my[1] + __uint_as_float(s1w.x & 0xFFFF0000u);
                        hh[2] = my[2] + __uint_as_float(s1w.y << 16);
                        hh[3] = my[3] + __uint_as_float(s1w.y & 0xFFFF0000u);
                        acc[t] += (hh[0] + hh[1]) + (hh[2] + hh[3]);
                        #pragma unroll
                        for (int s2 = 0; s2 < 4; ++s2)
                            *(ushort*)(dst + sto[t][s2]) = f2bf(hh[s2]);
                    }
                }
            }
        } else if (role == 3) {                      // S4 quads 2b-6, 2b-5
            #pragma unroll
            for (int u = 0; u < 2; ++u) {
                const int q = 2 * b - 6 + u;
                if (steady || (q >= 0 && q <= 63)) {
                    const char* src = sb_h + (((2 * jm + u + 2) & 7) << 11);
                    bf16x8 a0 = *(const bf16x8*)(src + rdA[0]);
                    bf16x8 a1 = *(const bf16x8*)(src + rdA[1]);
                    char* dst = sb_s4 + (((2 * jm + u + 2) & 7) << 12);
                    #pragma unroll
                    for (int t = 0; t < 2; ++t) {
                        f32x4 c = {0, 0, 0, 0};
                        c = MFMA16(a0, wh[t*2+0], c); c = MFMA16(a0, wl[t*2+0], c);
                        c = MFMA16(a1, wh[t*2+1], c); c = MFMA16(a1, wl[t*2+1], c);
                        ushort my[4];
                        lif4u(c, bias[t], v[t], my);
                        #pragma unroll
                        for (int s2 = 0; s2 < 4; ++s2)
                            *(ushort*)(dst + sto[t][s2]) = my[s2];
                    }
                }
            }
        } else {                                     // S5 quads 2b-8, 2b-7
            #pragma unroll
            for (int u = 0; u < 2; ++u) {
                const int q = 2 * b - 8 + u;
                if (steady || q >= 0) {
                    const char* src = sb_s4 + (((2 * jm + u) & 7) << 12);
                    bf16x8 a4[4];
                    #pragma unroll
                    for (int kt = 0; kt < 4; ++kt)
                        a4[kt] = *(const bf16x8*)(src + rdB[kt]);
                    f32x4 c = {0, 0, 0, 0};
                    #pragma unroll
                    for (int kt = 0; kt < 4; ++kt) {
                        c = MFMA16(a4[kt], wh[kt], c);
                        c = MFMA16(a4[kt], wl[kt], c);
                    }
                    float my[4];
                    lif4(c, bias5, v5, my);
                    acc5 += (my[0] + my[1]) + (my[2] + my[3]);
                }
            }
        }
    };

    // ---------------- main loop: 36 beats, 1 barrier each ----------------
    // Straggler wave (role 0: S1+S5) runs at elevated scheduler priority
    // for the whole loop — targets barrier skew; no arithmetic change.
    if (role == 0) __builtin_amdgcn_s_setprio(1);
    for (int b = 0; b < 8; ++b) {                 // prologue (checked, curpre)
        do_beat2(b, b & 3, false, false); __syncthreads();
    }
    #pragma unroll 1
    for (int bb = 8; bb < 32; bb += 4) {          // steady (saturated S1)
        do_beat2(bb + 0, 0, true, true); __syncthreads();
        do_beat2(bb + 1, 1, true, true); __syncthreads();
        do_beat2(bb + 2, 2, true, true); __syncthreads();
        do_beat2(bb + 3, 3, true, true); __syncthreads();
    }
    for (int b = 32; b < 36; ++b) {               // epilogue (checked drain)
        do_beat2(b, b & 3, false, true); __syncthreads();
    }
    if (role == 0) __builtin_amdgcn_s_setprio(0);

    // ---------------- epilogue: fold the linear tail ----------------
    // Out[n,c] = Weff.S5 + W2eff.Smid + 256*(fc_b + fc_w.(wo.bv+bo) + Weff.r2_db)
    float* scr   = curpre;                // curpre dead -> scratch
    float* S5lds = scr;                   // [4][128]
    float* Smlds = scr + 512;             // [4][64]
    float* ubuf  = scr + 768;             // [128]
    float* tmp   = scr + 896;             // [10][128]
    float* Weff  = scr + 2176;            // [10][128]
    float* W2eff = scr + 3456;            // [10][64]
    float* bcon  = scr + 4096;            // [10]

    if (role == 2) {
        #pragma unroll
        for (int t = 0; t < 2; ++t)
            Smlds[g * 64 + (bt + t) * 16 + l16] = acc[t];
    } else if (role == 4 || role == 0) {
        S5lds[g * 128 + t5 * 16 + l16] = acc5;
    }
    if (tid < 128) {
        float a = bo[tid];
        for (int m = 0; m < 128; ++m) a = fmaf(wo[tid * 128 + m], bv[m], a);
        ubuf[tid] = a;
    }
    for (int idx = tid; idx < 1280; idx += NTHREADS) {
        int c = idx >> 7, k = idx & 127;
        float a = 0.0f;
        for (int m = 0; m < 128; ++m) a = fmaf(fc_w[c * 128 + m], wo[m * 128 + k], a);
        tmp[idx] = a;
    }
    __syncthreads();
    for (int idx = tid; idx < 1280; idx += NTHREADS) {
        int c = idx >> 7, j = idx & 127;
        float a = 0.0f;
        for (int k = 0; k < 128; ++k) a = fmaf(tmp[c * 128 + k], wv[k * 128 + j], a);
        Weff[idx] = a;
    }
    __syncthreads();
    for (int idx = tid; idx < 640; idx += NTHREADS) {
        int c = idx >> 6, m = idx & 63;
        float a = 0.0f;
        for (int j = 0; j < 128; ++j) a = fmaf(Weff[c * 128 + j], r2_dw[j * 64 + m], a);
        W2eff[idx] = a;
    }
    if (tid < 10) {
        float a = fc_b[tid];
        for (int k = 0; k < 128; ++k) a = fmaf(fc_w[tid * 128 + k], ubuf[k], a);
        for (int j = 0; j < 128; ++j) a = fmaf(Weff[tid * 128 + j], r2_db[j], a);
        bcon[tid] = a;
    }
    __syncthreads();
    if (tid < 40) {
        int r = tid / 10, c = tid - r * 10;
        float a = 256.0f * bcon[c];
        for (int j = 0; j < 128; ++j) a = fmaf(Weff[c * 128 + j], S5lds[r * 128 + j], a);
        for (int m = 0; m < 64;  ++m) a = fmaf(W2eff[c * 64 + m], Smlds[r * 64 + m], a);
        out[(blk * 4 + r) * 10 + c] = a;
    }
}

extern "C" void kernel_launch(void* const* d_in, const int* in_sizes, int n_in,
                              void* d_out, int out_size, void* d_ws, size_t ws_size,
                              hipStream_t stream) {
    (void)in_sizes; (void)n_in; (void)d_ws; (void)ws_size; (void)out_size;
    const float* x     = (const float*)d_in[0];
    const float* l1_w  = (const float*)d_in[1];
    const float* l1_b  = (const float*)d_in[2];
    const float* r1_w1 = (const float*)d_in[3];
    const float* r1_b1 = (const float*)d_in[4];
    const float* r1_w2 = (const float*)d_in[5];
    const float* r1_b2 = (const float*)d_in[6];
    const float* r2_w1 = (const float*)d_in[7];
    const float* r2_b1 = (const float*)d_in[8];
    const float* r2_w2 = (const float*)d_in[9];
    const float* r2_b2 = (const float*)d_in[10];
    const float* r2_dw = (const float*)d_in[11];
    const float* r2_db = (const float*)d_in[12];
    const float* wv    = (const float*)d_in[13];
    const float* bv    = (const float*)d_in[14];
    const float* wo    = (const float*)d_in[15];
    const float* bo    = (const float*)d_in[16];
    const float* fc_w  = (const float*)d_in[17];
    const float* fc_b  = (const float*)d_in[18];

    snn_oct<<<dim3(NBLOCKS), dim3(NTHREADS), 0, stream>>>(
        x, l1_w, l1_b, r1_w1, r1_b1, r1_w2, r1_b2,
        r2_w1, r2_b1, r2_w2, r2_b2, r2_dw, r2_db,
        wv, bv, wo, bo, fc_w, fc_b, (float*)d_out);
}

// Round 9
// 76.186 us; speedup vs baseline: 1.0604x; 1.0604x over previous
//
#include <hip/hip_runtime.h>

#define NTHREADS 1024
#define NBLOCKS 256

typedef short bf16x8 __attribute__((ext_vector_type(8)));
typedef short bf16x4 __attribute__((ext_vector_type(4)));
typedef float f32x4  __attribute__((ext_vector_type(4)));
#define MFMA16(a,b,c) __builtin_amdgcn_mfma_f32_16x16x32_bf16(a,b,c,0,0,0)

// split-bf16: hi = rtne_bf16(w), lo = rtne_bf16(w - hi); hi+lo ~ w to 2^-17
__device__ __forceinline__ void splitbf(float f, ushort& h, ushort& l) {
    unsigned u = __float_as_uint(f);
    unsigned r = u + 0x7FFFu + ((u >> 16) & 1u);
    h = (ushort)(r >> 16);
    float fl = f - __uint_as_float(((unsigned)h) << 16);
    unsigned ul = __float_as_uint(fl);
    unsigned rl = ul + 0x7FFFu + ((ul >> 16) & 1u);
    l = (ushort)(rl >> 16);
}

__device__ __forceinline__ void load_wfrag(const float* __restrict__ Wrow,
                                           bf16x8& hi, bf16x8& lo) {
    #pragma unroll
    for (int j = 0; j < 8; ++j) {
        ushort h, l;
        splitbf(Wrow[j], h, l);
        hi[j] = (short)h;
        lo[j] = (short)l;
    }
}

// exact f32->bf16 bit-truncate: valid for exactly-representable values (0,1,2)
__device__ __forceinline__ ushort f2bf(float f) {
    return (ushort)(__float_as_uint(f) >> 16);
}

// In-lane 4-step LIF, float spikes out (identical rounding to all rounds)
__device__ __forceinline__ void lif4(const f32x4& c, float bias,
                                     float& v, float* __restrict__ my) {
    #pragma unroll
    for (int s2 = 0; s2 < 4; ++s2) {
        float cur = c[s2] + bias;
        float vn = fmaf(0.5f, cur - v, v);
        bool fire = (vn >= 1.0f);
        v = fire ? 0.0f : vn;
        my[s2] = fire ? 1.0f : 0.0f;
    }
}

// In-lane 4-step LIF, bf16 spike words out (0x3F80 == bf16(1.0))
__device__ __forceinline__ void lif4u(const f32x4& c, float bias,
                                      float& v, ushort* __restrict__ my) {
    #pragma unroll
    for (int s2 = 0; s2 < 4; ++s2) {
        float cur = c[s2] + bias;
        float vn = fmaf(0.5f, cur - v, v);
        bool fire = (vn >= 1.0f);
        v = fire ? 0.0f : vn;
        my[s2] = fire ? (ushort)0x3F80 : (ushort)0;
    }
}

// pack 4 exactly-representable floats to 4 bf16 and store 8B
__device__ __forceinline__ void pack_store4(char* addr, const float* m) {
    uint2 w;
    w.x = (__float_as_uint(m[0]) >> 16) | (__float_as_uint(m[1]) & 0xFFFF0000u);
    w.y = (__float_as_uint(m[2]) >> 16) | (__float_as_uint(m[3]) & 0xFFFF0000u);
    *(uint2*)addr = w;
}

// 16-wave in-lane-LIF pipeline, 2 quads (8 steps) per barrier, literal ring
// phases: 256 blocks x 1024 threads, 4 batch rows/block, 4 waves/SIMD.
// Spike tiles [16 slots][K] bf16, slot = 4*brow + step. ALL rings depth-8
// quads (slot = quad & 7; >=3-barrier read->rewrite margin, replay-safe).
// Beat b processes quads {2b-LAG, 2b-LAG+1}, LAG = 0/2/4/6/8 for
// S1/S2/S3/S4/S5. 36 beats, ONE barrier each. Roles: W0-1:S1(2 tiles)+S5
// tile 6/7  W2-3:S2  W4-5:S3+h  W6-9:S4  W10-15:S5.
// Phase 1 (layer-1 window precompute) is MFMA-based: Toeplitz X staged as
// 4 shifted bf16 copies, split-bf16 weights, 3-term product.
//
// FINAL (R9): byte-exact recovery of the verified 76.2us R2 artifact.
// Isolated-experiment ledger on this body (all reverted): SIMD role-remap
// -2.0us (R6), dual hi/lo accumulators -3.4us (R7), persistent role-0
// s_setprio -4.6us (R8), R3 combined extras -27us (scratch spill).
// The ~4700cyc/beat is structural barrier-drain+LDS-latency skew of the
// 36-barrier lockstep design; fused beats (1-barrier ring margin = R0
// replay race) and 2 blocks/CU (l1_w staging 59KB > halved ring budget)
// are both disqualified. Plateau of this structure, not a HW roofline.
__global__ __launch_bounds__(NTHREADS, 1) void snn_oct(
    const float* __restrict__ x,
    const float* __restrict__ l1_w,  const float* __restrict__ l1_b,
    const float* __restrict__ r1_w1, const float* __restrict__ r1_b1,
    const float* __restrict__ r1_w2, const float* __restrict__ r1_b2,
    const float* __restrict__ r2_w1, const float* __restrict__ r2_b1,
    const float* __restrict__ r2_w2, const float* __restrict__ r2_b2,
    const float* __restrict__ r2_dw, const float* __restrict__ r2_db,
    const float* __restrict__ wv,    const float* __restrict__ bv,
    const float* __restrict__ wo,    const float* __restrict__ bo,
    const float* __restrict__ fc_w,  const float* __restrict__ fc_b,
    float* __restrict__ out)
{
    // curpre: [14 quad][4 brow][64 n][4 s] f32 = 57344 B; epilogue scratch.
    __shared__ __align__(16) float curpre[14 * 1024];
    // main loop: s1[8][2048] | cp[8][2048] | s2[8][2048] | h[8][2048] | s4[8][4096]
    // phase 0/1 staging (aliased, dead before main loop):
    //   [0,4608) xstage f32 [4][288] | [4608,23296) x bf16 4-shift copies
    //   [23296,82688) l1_w split bf16 (stride 232) | [82688,82944) l1_b f32
    __shared__ __align__(16) char sbuf[98304];

    const int tid  = threadIdx.x;
    const int blk  = blockIdx.x;
    const int lane = tid & 63;
    const int wvi  = tid >> 6;         // wave 0..15
    const int g    = lane >> 4;        // k-group (consumer) / brow (producer)
    const int l16  = lane & 15;        // A-row slot (consumer) / neuron (D col)

    char* sb_s1 = sbuf;                // 8 x 2048
    char* sb_cp = sbuf + 16384;        // 8 x 2048 (uint2 per (tile,g,l16))
    char* sb_s2 = sbuf + 32768;        // 8 x 2048
    char* sb_h  = sbuf + 49152;        // 8 x 2048
    char* sb_s4 = sbuf + 65536;        // 8 x 4096

    // ---------------- phase 0: stage x (f32) + split-bf16 l1 weights -------
    {
        float* xstage = (float*)sbuf;    // [4][288]
        for (int idx = tid; idx < 4 * 288; idx += NTHREADS) {
            int r = idx / 288, tt2 = idx - r * 288;
            xstage[idx] = (tt2 < 256) ? x[(blk * 4 + r) * 256 + tt2] : 0.0f;
        }
        uint* whw = (uint*)(sbuf + 23296);
        uint* wlw = (uint*)(sbuf + 52992);
        for (int idx = tid; idx < 64 * 116; idx += NTHREADS) {
            int n = idx / 116, kp = idx - n * 116;
            int k0 = kp * 2;
            float f0 = (k0 < 201)     ? l1_w[n * 201 + k0]     : 0.0f;
            float f1 = (k0 + 1 < 201) ? l1_w[n * 201 + k0 + 1] : 0.0f;
            ushort h0, l0, h1, l1v;
            splitbf(f0, h0, l0); splitbf(f1, h1, l1v);
            whw[(n * 232 + k0) >> 1] = (uint)h0 | ((uint)h1 << 16);
            wlw[(n * 232 + k0) >> 1] = (uint)l0 | ((uint)l1v << 16);
        }
        if (tid < 64) ((float*)(sbuf + 82688))[tid] = l1_b[tid];
    }
    __syncthreads();

    // ---------------- phase 0b: build 4 shifted bf16 copies of x ----------
    {
        const float* xstage = (const float*)sbuf;
        for (int idx = tid; idx < 4 * 4 * 144; idx += NTHREADS) {
            int c = idx / 576;              // shift 0..3
            int rem = idx - c * 576;
            int r = rem / 144, ep = rem - r * 144;
            int i0 = ep * 2;
            int j0 = i0 + c;
            float f0 = (j0 < 288)     ? xstage[r * 288 + j0]     : 0.0f;
            float f1 = (j0 + 1 < 288) ? xstage[r * 288 + j0 + 1] : 0.0f;
            ushort h0, l0, h1, l1v;
            splitbf(f0, h0, l0); splitbf(f1, h1, l1v);
            *(uint*)(sbuf + 4608 + (c * 4 + r) * 584 + i0 * 2) =
                (uint)h0 | ((uint)h1 << 16);
            *(uint*)(sbuf + 4608 + (16 + c * 4 + r) * 584 + i0 * 2) =
                (uint)l0 | ((uint)l1v << 16);
        }
    }
    __syncthreads();

    // ---------------- phase 1: layer-1 precompute via MFMA ----------------
    {
        const int r1 = wvi & 3;
        const int tt = wvi >> 2;
        const int t0 = tt << 4;
        const int cc2 = l16 & 3;
        const char* xh_base = sbuf + 4608 + (cc2 * 4 + r1) * 584;
        const char* xl_base = xh_base + 16 * 584;
        const int eb = (t0 + (l16 & ~3) + g * 8) * 2;
        const char* whb = sbuf + 23296 + (l16 * 232 + g * 8) * 2;
        const char* wlb = whb + 29696;
        const float* blds = (const float*)(sbuf + 82688);

        f32x4 accp[4];
        #pragma unroll
        for (int nt = 0; nt < 4; ++nt)
            accp[nt] = *(const f32x4*)(blds + nt * 16 + g * 4);

        #pragma unroll
        for (int kt = 0; kt < 7; ++kt) {
            const int xo = eb + kt * 64;
            bf16x4 ha = *(const bf16x4*)(xh_base + xo);
            bf16x4 hb = *(const bf16x4*)(xh_base + xo + 8);
            bf16x4 la = *(const bf16x4*)(xl_base + xo);
            bf16x4 lb = *(const bf16x4*)(xl_base + xo + 8);
            bf16x8 xh8 = __builtin_shufflevector(ha, hb, 0, 1, 2, 3, 4, 5, 6, 7);
            bf16x8 xl8 = __builtin_shufflevector(la, lb, 0, 1, 2, 3, 4, 5, 6, 7);
            #pragma unroll
            for (int nt = 0; nt < 4; ++nt) {
                const int wo2 = nt * 7424 + kt * 64;
                bf16x8 wwh = *(const bf16x8*)(whb + wo2);
                bf16x8 wwl = *(const bf16x8*)(wlb + wo2);
                accp[nt] = MFMA16(wwh, xh8, accp[nt]);
                accp[nt] = MFMA16(wwh, xl8, accp[nt]);
                accp[nt] = MFMA16(wwl, xh8, accp[nt]);
            }
        }
        if (!(tt == 3 && l16 >= 8)) {
            const int t = t0 + l16;
            float* cp = curpre + (t >> 2) * 1024 + r1 * 256 + (t & 3);
            #pragma unroll
            for (int nt = 0; nt < 4; ++nt) {
                #pragma unroll
                for (int j = 0; j < 4; ++j)
                    cp[(nt * 16 + g * 4 + j) * 4] = accp[nt][j];
            }
        }
    }
    __syncthreads();

    // ---------------- consumer A-read addressing (XOR-swizzled) ----------
    const int XS = (l16 & 7) << 4;
    int rdA[2], rdB[4];
    #pragma unroll
    for (int kt = 0; kt < 2; ++kt)
        rdA[kt] = (l16 << 7) + (((kt << 6) | (g << 4)) ^ XS);
    #pragma unroll
    for (int kt = 0; kt < 4; ++kt)
        rdB[kt] = (l16 << 8) + (((kt << 6) | (g << 4)) ^ XS);

    // ---------------- roles + weights (uniform small register file) -------
    int role, bt;
    if (wvi < 2)       { role = 0; bt = wvi * 2; }        // S1 + S5 tile 6+wvi
    else if (wvi < 4)  { role = 1; bt = (wvi - 2) * 2; }
    else if (wvi < 6)  { role = 2; bt = (wvi - 4) * 2; }
    else if (wvi < 10) { role = 3; bt = (wvi - 6) * 2; }
    else               { role = 4; bt = wvi - 10; }

    bf16x8 wh[4], wl[4];
    float bias[2] = {0, 0};
    float bias5 = 0.0f;
    int t5 = 0;
    if (role == 1 || role == 2) {
        const float* W = (role == 1) ? r1_w1 : r1_w2;
        const float* B = (role == 1) ? r1_b1 : r1_b2;
        #pragma unroll
        for (int t = 0; t < 2; ++t) {
            #pragma unroll
            for (int kt = 0; kt < 2; ++kt)
                load_wfrag(W + ((bt + t) * 16 + l16) * 64 + kt * 32 + g * 8,
                           wh[t * 2 + kt], wl[t * 2 + kt]);
            bias[t] = B[(bt + t) * 16 + l16];
        }
    } else if (role == 3) {
        #pragma unroll
        for (int t = 0; t < 2; ++t) {
            #pragma unroll
            for (int kt = 0; kt < 2; ++kt)
                load_wfrag(r2_w1 + ((bt + t) * 16 + l16) * 64 + kt * 32 + g * 8,
                           wh[t * 2 + kt], wl[t * 2 + kt]);
            bias[t] = r2_b1[(bt + t) * 16 + l16];
        }
    } else {                               // role 0 (t5 = 6+wvi) or 4 (t5 = bt)
        t5 = (role == 0) ? (6 + wvi) : bt;
        #pragma unroll
        for (int kt = 0; kt < 4; ++kt)
            load_wfrag(r2_w2 + (t5 * 16 + l16) * 128 + kt * 32 + g * 8,
                       wh[kt], wl[kt]);
        bias5 = r2_b2[t5 * 16 + l16];
    }

    // ---------------- thread-invariant store offsets ----------------
    int sto[2][4];
    {
        const int rb = (role == 3) ? 8 : 7;
        #pragma unroll
        for (int t = 0; t < 2; ++t) {
            const int cb = ((bt + t) * 16 + l16) * 2;
            #pragma unroll
            for (int s2 = 0; s2 < 4; ++s2) {
                const int row = 4 * g + s2;
                sto[t][s2] = (row << rb) + (cb ^ ((row & 7) << 4));
            }
        }
    }
    const int cpb = (g << 7) + (l16 << 3);

    float v[2] = {0, 0}, acc[2] = {0, 0};
    float v5 = 0.0f, acc5 = 0.0f;
    float cur55[2] = {0, 0};

    // ---------------- beat body: 2 quads per stage, ring phase jm literal --
    auto do_beat2 = [&](const int b, const int jm, const bool steady,
                        const bool sat) __attribute__((always_inline)) {
        if (role == 0) {
            #pragma unroll
            for (int u = 0; u < 2; ++u) {            // S1 quads 2b, 2b+1
                const int q = 2 * b + u;
                if (steady || q <= 63) {
                    char* dst = sb_s1 + (((2 * jm + u) & 7) << 11);
                    char* cpy = sb_cp + (((2 * jm + u) & 7) << 11) + cpb;
                    #pragma unroll
                    for (int t = 0; t < 2; ++t) {
                        const int ta = bt + t;
                        f32x4 c;
                        if (!sat && q <= 13) {
                            c = *(const f32x4*)(curpre + (q << 10) + (g << 8) +
                                                ((ta * 16 + l16) << 2));
                            if (q == 13) cur55[t] = c[3];
                        } else {
                            c[0] = cur55[t]; c[1] = cur55[t];
                            c[2] = cur55[t]; c[3] = cur55[t];
                        }
                        float my[4];
                        lif4(c, 0.0f, v[t], my);
                        #pragma unroll
                        for (int s2 = 0; s2 < 4; ++s2)
                            *(ushort*)(dst + sto[t][s2]) = f2bf(my[s2]);
                        pack_store4(cpy + ta * 512, my);
                    }
                }
            }
            #pragma unroll
            for (int u = 0; u < 2; ++u) {            // S5 quads 2b-8, 2b-7
                const int q = 2 * b - 8 + u;
                if (steady || q >= 0) {
                    const char* src = sb_s4 + (((2 * jm + u) & 7) << 12);
                    bf16x8 a4[4];
                    #pragma unroll
                    for (int kt = 0; kt < 4; ++kt)
                        a4[kt] = *(const bf16x8*)(src + rdB[kt]);
                    f32x4 c = {0, 0, 0, 0};
                    #pragma unroll
                    for (int kt = 0; kt < 4; ++kt) {
                        c = MFMA16(a4[kt], wh[kt], c);
                        c = MFMA16(a4[kt], wl[kt], c);
                    }
                    float my5[4];
                    lif4(c, bias5, v5, my5);
                    acc5 += (my5[0] + my5[1]) + (my5[2] + my5[3]);
                }
            }
        } else if (role == 1) {                      // S2 quads 2b-2, 2b-1
            #pragma unroll
            for (int u = 0; u < 2; ++u) {
                const int q = 2 * b - 2 + u;
                if (steady || (q >= 0 && q <= 63)) {
                    const char* src = sb_s1 + (((2 * jm + u + 6) & 7) << 11);
                    bf16x8 a0 = *(const bf16x8*)(src + rdA[0]);
                    bf16x8 a1 = *(const bf16x8*)(src + rdA[1]);
                    char* dst = sb_s2 + (((2 * jm + u + 6) & 7) << 11);
                    #pragma unroll
                    for (int t = 0; t < 2; ++t) {
                        f32x4 c = {0, 0, 0, 0};
                        c = MFMA16(a0, wh[t*2+0], c); c = MFMA16(a0, wl[t*2+0], c);
                        c = MFMA16(a1, wh[t*2+1], c); c = MFMA16(a1, wl[t*2+1], c);
                        ushort my[4];
                        lif4u(c, bias[t], v[t], my);
                        #pragma unroll
                        for (int s2 = 0; s2 < 4; ++s2)
                            *(ushort*)(dst + sto[t][s2]) = my[s2];
                    }
                }
            }
        } else if (role == 2) {                      // S3 + h quads 2b-4, 2b-3
            #pragma unroll
            for (int u = 0; u < 2; ++u) {
                const int q = 2 * b - 4 + u;
                if (steady || (q >= 0 && q <= 63)) {
                    const char* src = sb_s2 + (((2 * jm + u + 4) & 7) << 11);
                    const char* cpy = sb_cp + (((2 * jm + u + 4) & 7) << 11) + cpb;
                    bf16x8 a0 = *(const bf16x8*)(src + rdA[0]);
                    bf16x8 a1 = *(const bf16x8*)(src + rdA[1]);
                    char* dst = sb_h + (((2 * jm + u + 4) & 7) << 11);
                    #pragma unroll
                    for (int t = 0; t < 2; ++t) {
                        const int ta = bt + t;
                        f32x4 c = {0, 0, 0, 0};
                        c = MFMA16(a0, wh[t*2+0], c); c = MFMA16(a0, wl[t*2+0], c);
                        c = MFMA16(a1, wh[t*2+1], c); c = MFMA16(a1, wl[t*2+1], c);
                        float my[4];
                        lif4(c, bias[t], v[t], my);
                        const uint2 s1w = *(const uint2*)(cpy + ta * 512);
                        float hh[4];
                        hh[0] = my[0] + __uint_as_float(s1w.x << 16);
                        hh[1] = my[1] + __uint_as_float(s1w.x & 0xFFFF0000u);
                        hh[2] = my[2] + __uint_as_float(s1w.y << 16);
                        hh[3] = my[3] + __uint_as_float(s1w.y & 0xFFFF0000u);
                        acc[t] += (hh[0] + hh[1]) + (hh[2] + hh[3]);
                        #pragma unroll
                        for (int s2 = 0; s2 < 4; ++s2)
                            *(ushort*)(dst + sto[t][s2]) = f2bf(hh[s2]);
                    }
                }
            }
        } else if (role == 3) {                      // S4 quads 2b-6, 2b-5
            #pragma unroll
            for (int u = 0; u < 2; ++u) {
                const int q = 2 * b - 6 + u;
                if (steady || (q >= 0 && q <= 63)) {
                    const char* src = sb_h + (((2 * jm + u + 2) & 7) << 11);
                    bf16x8 a0 = *(const bf16x8*)(src + rdA[0]);
                    bf16x8 a1 = *(const bf16x8*)(src + rdA[1]);
                    char* dst = sb_s4 + (((2 * jm + u + 2) & 7) << 12);
                    #pragma unroll
                    for (int t = 0; t < 2; ++t) {
                        f32x4 c = {0, 0, 0, 0};
                        c = MFMA16(a0, wh[t*2+0], c); c = MFMA16(a0, wl[t*2+0], c);
                        c = MFMA16(a1, wh[t*2+1], c); c = MFMA16(a1, wl[t*2+1], c);
                        ushort my[4];
                        lif4u(c, bias[t], v[t], my);
                        #pragma unroll
                        for (int s2 = 0; s2 < 4; ++s2)
                            *(ushort*)(dst + sto[t][s2]) = my[s2];
                    }
                }
            }
        } else {                                     // S5 quads 2b-8, 2b-7
            #pragma unroll
            for (int u = 0; u < 2; ++u) {
                const int q = 2 * b - 8 + u;
                if (steady || q >= 0) {
                    const char* src = sb_s4 + (((2 * jm + u) & 7) << 12);
                    bf16x8 a4[4];
                    #pragma unroll
                    for (int kt = 0; kt < 4; ++kt)
                        a4[kt] = *(const bf16x8*)(src + rdB[kt]);
                    f32x4 c = {0, 0, 0, 0};
                    #pragma unroll
                    for (int kt = 0; kt < 4; ++kt) {
                        c = MFMA16(a4[kt], wh[kt], c);
                        c = MFMA16(a4[kt], wl[kt], c);
                    }
                    float my[4];
                    lif4(c, bias5, v5, my);
                    acc5 += (my[0] + my[1]) + (my[2] + my[3]);
                }
            }
        }
    };

    // ---------------- main loop: 36 beats, 1 barrier each ----------------
    for (int b = 0; b < 8; ++b) {                 // prologue (checked, curpre)
        do_beat2(b, b & 3, false, false); __syncthreads();
    }
    #pragma unroll 1
    for (int bb = 8; bb < 32; bb += 4) {          // steady (saturated S1)
        do_beat2(bb + 0, 0, true, true); __syncthreads();
        do_beat2(bb + 1, 1, true, true); __syncthreads();
        do_beat2(bb + 2, 2, true, true); __syncthreads();
        do_beat2(bb + 3, 3, true, true); __syncthreads();
    }
    for (int b = 32; b < 36; ++b) {               // epilogue (checked drain)
        do_beat2(b, b & 3, false, true); __syncthreads();
    }

    // ---------------- epilogue: fold the linear tail ----------------
    // Out[n,c] = Weff.S5 + W2eff.Smid + 256*(fc_b + fc_w.(wo.bv+bo) + Weff.r2_db)
    float* scr   = curpre;                // curpre dead -> scratch
    float* S5lds = scr;                   // [4][128]
    float* Smlds = scr + 512;             // [4][64]
    float* ubuf  = scr + 768;             // [128]
    float* tmp   = scr + 896;             // [10][128]
    float* Weff  = scr + 2176;            // [10][128]
    float* W2eff = scr + 3456;            // [10][64]
    float* bcon  = scr + 4096;            // [10]

    if (role == 2) {
        #pragma unroll
        for (int t = 0; t < 2; ++t)
            Smlds[g * 64 + (bt + t) * 16 + l16] = acc[t];
    } else if (role == 4 || role == 0) {
        S5lds[g * 128 + t5 * 16 + l16] = acc5;
    }
    if (tid < 128) {
        float a = bo[tid];
        for (int m = 0; m < 128; ++m) a = fmaf(wo[tid * 128 + m], bv[m], a);
        ubuf[tid] = a;
    }
    for (int idx = tid; idx < 1280; idx += NTHREADS) {
        int c = idx >> 7, k = idx & 127;
        float a = 0.0f;
        for (int m = 0; m < 128; ++m) a = fmaf(fc_w[c * 128 + m], wo[m * 128 + k], a);
        tmp[idx] = a;
    }
    __syncthreads();
    for (int idx = tid; idx < 1280; idx += NTHREADS) {
        int c = idx >> 7, j = idx & 127;
        float a = 0.0f;
        for (int k = 0; k < 128; ++k) a = fmaf(tmp[c * 128 + k], wv[k * 128 + j], a);
        Weff[idx] = a;
    }
    __syncthreads();
    for (int idx = tid; idx < 640; idx += NTHREADS) {
        int c = idx >> 6, m = idx & 63;
        float a = 0.0f;
        for (int j = 0; j < 128; ++j) a = fmaf(Weff[c * 128 + j], r2_dw[j * 64 + m], a);
        W2eff[idx] = a;
    }
    if (tid < 10) {
        float a = fc_b[tid];
        for (int k = 0; k < 128; ++k) a = fmaf(fc_w[tid * 128 + k], ubuf[k], a);
        for (int j = 0; j < 128; ++j) a = fmaf(Weff[tid * 128 + j], r2_db[j], a);
        bcon[tid] = a;
    }
    __syncthreads();
    if (tid < 40) {
        int r = tid / 10, c = tid - r * 10;
        float a = 256.0f * bcon[c];
        for (int j = 0; j < 128; ++j) a = fmaf(Weff[c * 128 + j], S5lds[r * 128 + j], a);
        for (int m = 0; m < 64;  ++m) a = fmaf(W2eff[c * 64 + m], Smlds[r * 64 + m], a);
        out[(blk * 4 + r) * 10 + c] = a;
    }
}

extern "C" void kernel_launch(void* const* d_in, const int* in_sizes, int n_in,
                              void* d_out, int out_size, void* d_ws, size_t ws_size,
                              hipStream_t stream) {
    (void)in_sizes; (void)n_in; (void)d_ws; (void)ws_size; (void)out_size;
    const float* x     = (const float*)d_in[0];
    const float* l1_w  = (const float*)d_in[1];
    const float* l1_b  = (const float*)d_in[2];
    const float* r1_w1 = (const float*)d_in[3];
    const float* r1_b1 = (const float*)d_in[4];
    const float* r1_w2 = (const float*)d_in[5];
    const float* r1_b2 = (const float*)d_in[6];
    const float* r2_w1 = (const float*)d_in[7];
    const float* r2_b1 = (const float*)d_in[8];
    const float* r2_w2 = (const float*)d_in[9];
    const float* r2_b2 = (const float*)d_in[10];
    const float* r2_dw = (const float*)d_in[11];
    const float* r2_db = (const float*)d_in[12];
    const float* wv    = (const float*)d_in[13];
    const float* bv    = (const float*)d_in[14];
    const float* wo    = (const float*)d_in[15];
    const float* bo    = (const float*)d_in[16];
    const float* fc_w  = (const float*)d_in[17];
    const float* fc_b  = (const float*)d_in[18];

    snn_oct<<<dim3(NBLOCKS), dim3(NTHREADS), 0, stream>>>(
        x, l1_w, l1_b, r1_w1, r1_b1, r1_w2, r1_b2,
        r2_w1, r2_b1, r2_w2, r2_b2, r2_dw, r2_db,
        wv, bv, wo, bo, fc_w, fc_b, (float*)d_out);
}